// Round 11
// baseline (3621.442 us; speedup 1.0000x reference)
//
#include <hip/hip_runtime.h>

#define TSTEPS 2048
#define PPB 16          // paths per block
#define NT 512          // 8 waves: m = wv&1 (MLP), nt = wv>>1 (column tile)
#define KAPPA 2.72f
#define THETA -3.5f

typedef _Float16 half8 __attribute__((ext_vector_type(8)));
typedef __fp16 fp16x2 __attribute__((ext_vector_type(2)));
typedef float f32x4 __attribute__((ext_vector_type(4)));

__device__ __forceinline__ float ftanh(float x) {
    float e = __expf(2.0f * x);                        // native v_exp path
    return 1.0f - 2.0f * __builtin_amdgcn_rcpf(e + 1.0f);
}
__device__ __forceinline__ float fsigm(float x) {
    float e = __expf(-x);
    return __builtin_amdgcn_rcpf(1.0f + e);
}
__device__ __forceinline__ f32x4 mm(half8 a, half8 b, f32x4 c) {
    return __builtin_amdgcn_mfma_f32_16x16x32_f16(a, b, c, 0, 0, 0);
}
__device__ __forceinline__ void wsplit(float v, _Float16& h, _Float16& l) {
    h = (_Float16)v; l = (_Float16)(v - (float)h);
}

// LDS f16 activation rows: [row 0..15][slot 0..7][elem 0..7], slot = chunk ^ (row&7).

__global__ __launch_bounds__(NT, 4) void sim_kernel(
    const float* __restrict__ init_var, const float* __restrict__ dtp,
    const float* __restrict__ dwg,
    const float* __restrict__ dW0, const float* __restrict__ dB0,
    const float* __restrict__ dW1, const float* __restrict__ dB1,
    const float* __restrict__ dW2, const float* __restrict__ dB2,
    const float* __restrict__ dW3, const float* __restrict__ dB3,
    const float* __restrict__ fW0, const float* __restrict__ fB0,
    const float* __restrict__ fW1, const float* __restrict__ fB1,
    const float* __restrict__ fW2, const float* __restrict__ fB2,
    const float* __restrict__ fW3, const float* __restrict__ fB3,
    float* __restrict__ out)
{
    __shared__ __align__(16) _Float16 hA[2][1024];
    __shared__ __align__(16) _Float16 hB[2][1024];
    __shared__ __align__(16) _Float16 hC[2][1024];

    const int tid  = threadIdx.x;
    const int lane = tid & 63;
    const int wv   = tid >> 6;        // 0..7
    const int m    = wv & 1;          // own MLP (0=drift, 1=diff)
    const int nt   = wv >> 1;         // 0..3 column tile
    const int l15  = lane & 15;
    const int lg   = lane >> 4;       // 0..3
    const int col  = nt * 16 + l15;   // column within own MLP
    const int q    = l15 & 7;

    const int roff0 = l15 * 64 + ((lg ^ q) << 3);         // chunks 0-3 (K 0..31)
    const int roff1 = l15 * 64 + (((4 + lg) ^ q) << 3);   // chunks 4-7 (K 32..63)
    int woff[4];
#pragma unroll
    for (int r = 0; r < 4; ++r) {
        const int wrow = lg * 4 + r;
        woff[r] = wrow * 64 + ((((col >> 3) ^ (wrow & 7))) << 3) + (col & 7);
    }

    // own-MLP weight pointers
    const float* W0 = m ? fW0 : dW0;
    const float* B0 = m ? fB0 : dB0;
    const float* W1 = m ? fW1 : dW1;
    const float* B1 = m ? fB1 : dB1;
    const float* W2 = m ? fW2 : dW2;
    const float* B2 = m ? fB2 : dB2;

    // ---------------- B-fragments (own MLP) + w3 (both): 10 frags = 40 VGPR ----------------
    // L0 packed-K: A has K0..15 = x_hi, K16..31 = x_lo; 2 MFMAs (W0hi, W0lo) = exact x*W0.
    half8 b0h, b0l;
#pragma unroll
    for (int i = 0; i < 8; ++i) {
        const int idx = (lg & 1) * 8 + i;
        const float v = (idx < 15) ? W0[col * 15 + idx] : 0.f;
        _Float16 h, l; wsplit(v, h, l);
        b0h[i] = h; b0l[i] = l;
    }
    half8 b1h0, b1h1, b2h0, b2h1;
#pragma unroll
    for (int i = 0; i < 8; ++i) {
        const int ka = lg * 8 + i, kb = 32 + lg * 8 + i;
        b1h0[i] = (_Float16)W1[col * 64 + ka];
        b1h1[i] = (_Float16)W1[col * 64 + kb];
        b2h0[i] = (_Float16)W2[col * 64 + ka];
        b2h1[i] = (_Float16)W2[col * 64 + kb];
    }
    // L3 A-fragments for BOTH MLPs: A[r][k] = w3[k] (row-invariant) ->
    // C[r][p] = od[p] in every lane with l15=p. No shuffles.
    half8 w3d0, w3d1, w3f0, w3f1;
#pragma unroll
    for (int i = 0; i < 8; ++i) {
        const int ka = lg * 8 + i, kb = 32 + lg * 8 + i;
        w3d0[i] = (_Float16)dW3[ka];
        w3d1[i] = (_Float16)dW3[kb];
        w3f0[i] = (_Float16)fW3[ka];
        w3f1[i] = (_Float16)fW3[kb];
    }
    // Pin fragments so their load+split chains can't be rematerialized in-loop.
    asm volatile("" : "+v"(b0h), "+v"(b0l));
    asm volatile("" : "+v"(b1h0), "+v"(b1h1), "+v"(b2h0), "+v"(b2h1));
    asm volatile("" : "+v"(w3d0), "+v"(w3d1), "+v"(w3f0), "+v"(w3f1));

    const float bias0 = B0[col], bias1 = B1[col], bias2 = B2[col];
    const float b3d = dB3[0], b3f = fB3[0];
    const float dt  = dtp[0];
    const float hdt  = 0.5f * dt;        // dx/2 (time comp)
    const float c6dt = dt * (1.0f / 6.0f);
    const float kdt  = KAPPA * dt;
    const float o0   = dt * dt;

    // ---------------- replicated per-lane state (p = l15) ----------------
    const int p = l15;
    const int path = blockIdx.x * PPB + p;
    const size_t pathT = (size_t)path * TSTEPS;
    const float* dwp = dwg + pathT;
    float iv = fminf(fmaxf(init_var[path], 0.01f), 1.5f);
    float lv = __logf(iv);
    float s1a0 = 0.f, s1a1 = 0.f;
    float s2a0 = 0.f, s2a1 = 0.f, s2a2 = 0.f, s2a3 = 0.f;
    float s3a0 = 0.f, s3a1 = 0.f, s3a2 = 0.f, s3a3 = 0.f;
    float s3a4 = 0.f, s3a5 = 0.f, s3a6 = 0.f, s3a7 = 0.f;

    const bool selHi = (lg & 1) != 0;   // lane's L0 A-frag covers x[8..15]
    const bool selLo = (lg & 2) != 0;   // lane's L0 A-frag carries the lo split

    union H8 { half8 v; fp16x2 p2[4]; uint4 u; };

    for (int t = 0; t < TSTEPS; ++t) {
        const float dwv = dwp[t];

        // ---- build L0 A-fragment in-register (pkrtz-packed hi/lo) ----
        half8 a0;
        {
            float xv[8];
            xv[0] = selHi ? s3a2 : s1a0;
            xv[1] = selHi ? s3a3 : s1a1;
            xv[2] = selHi ? s3a4 : s2a0;
            xv[3] = selHi ? s3a5 : s2a1;
            xv[4] = selHi ? s3a6 : s2a2;
            xv[5] = selHi ? s3a7 : s2a3;
            xv[6] = selHi ? (lv + 4.0f) : s3a0;
            xv[7] = selHi ? 0.f : s3a1;
            H8 hi, lo, a;
#pragma unroll
            for (int j = 0; j < 4; ++j)
                hi.p2[j] = __builtin_amdgcn_cvt_pkrtz(xv[2 * j], xv[2 * j + 1]);
#pragma unroll
            for (int j = 0; j < 4; ++j) {
                const float r0 = xv[2 * j]     - (float)hi.p2[j][0];
                const float r1 = xv[2 * j + 1] - (float)hi.p2[j][1];
                lo.p2[j] = __builtin_amdgcn_cvt_pkrtz(r0, r1);
            }
            a.u.x = selLo ? lo.u.x : hi.u.x;
            a.u.y = selLo ? lo.u.y : hi.u.y;
            a.u.z = selLo ? lo.u.z : hi.u.z;
            a.u.w = selLo ? lo.u.w : hi.u.w;
            a0 = a.v;
        }

        // ---- L0: x -> h0 (own MLP, 2 MFMA, exact hi/lo) ----
        {
            f32x4 c = {bias0, bias0, bias0, bias0};
            c = mm(a0, b0h, c);
            c = mm(a0, b0l, c);
#pragma unroll
            for (int r = 0; r < 4; ++r) hA[m][woff[r]] = (_Float16)ftanh(c[r]);
        }
        __syncthreads();

        // ---- L1: h0 -> h1 (own MLP) ----
        {
            const half8 a1 = *(const half8*)(&hA[m][roff0]);
            const half8 a2 = *(const half8*)(&hA[m][roff1]);
            f32x4 c = {bias1, bias1, bias1, bias1};
            c = mm(a1, b1h0, c);
            c = mm(a2, b1h1, c);
#pragma unroll
            for (int r = 0; r < 4; ++r) hB[m][woff[r]] = (_Float16)ftanh(c[r]);
        }
        __syncthreads();

        // ---- L2: h1 -> h2 (own MLP) ----
        {
            const half8 a1 = *(const half8*)(&hB[m][roff0]);
            const half8 a2 = *(const half8*)(&hB[m][roff1]);
            f32x4 c = {bias2, bias2, bias2, bias2};
            c = mm(a1, b2h0, c);
            c = mm(a2, b2h1, c);
#pragma unroll
            for (int r = 0; r < 4; ++r) hC[m][woff[r]] = (_Float16)ftanh(c[r]);
        }
        __syncthreads();

        // ---- L3 (every wave, both MLPs): od/of broadcast via w3-replicated A ----
        float od, of;
        {
            const half8 bd0 = *(const half8*)(&hC[0][roff0]);
            const half8 bd1 = *(const half8*)(&hC[0][roff1]);
            const half8 bf0 = *(const half8*)(&hC[1][roff0]);
            const half8 bf1 = *(const half8*)(&hC[1][roff1]);
            f32x4 c3d = {0.f, 0.f, 0.f, 0.f}, c3f = {0.f, 0.f, 0.f, 0.f};
            c3d = mm(w3d0, bd0, c3d);  c3f = mm(w3f0, bf0, c3f);
            c3d = mm(w3d1, bd1, c3d);  c3f = mm(w3f1, bf1, c3f);
            od = c3d[0] + b3d;          // same value in all C rows
            of = c3f[0] + b3f;
        }

        // ---- replicated state update (all lanes, p = l15), compressed algebra ----
        {
            const float drift_nn = 0.5f * ftanh(od);
            const float diffu = fmaf(1.5f, fsigm(of), 0.1f);
            float lvn = lv + kdt * (THETA - lv) + drift_nn * dt + diffu * dwv;
            lvn = fminf(fmaxf(lvn, -5.0f), 1.0f);
            const float d = lvn - lv;
            const float o1 = dt * d, o3 = d * d;
            // s3 += outer(s2_old, dx) + outer(g, oxx),  g = s1_old/2 + dx/6
            const float g0 = fmaf(0.5f, s1a0, c6dt);
            const float g1 = fmaf(0.5f, s1a1, (1.0f / 6.0f) * d);
            s3a0 = fmaf(s2a0, dt, fmaf(g0, o0, s3a0));
            s3a1 = fmaf(s2a0, d,  fmaf(g0, o1, s3a1));
            s3a2 = fmaf(s2a1, dt, fmaf(g0, o1, s3a2));
            s3a3 = fmaf(s2a1, d,  fmaf(g0, o3, s3a3));
            s3a4 = fmaf(s2a2, dt, fmaf(g1, o0, s3a4));
            s3a5 = fmaf(s2a2, d,  fmaf(g1, o1, s3a5));
            s3a6 = fmaf(s2a3, dt, fmaf(g1, o1, s3a6));
            s3a7 = fmaf(s2a3, d,  fmaf(g1, o3, s3a7));
            // s2 += outer(s1_old + dx/2, dx)
            const float e0 = s1a0 + hdt;
            const float e1 = fmaf(0.5f, d, s1a1);
            s2a0 = fmaf(e0, dt, s2a0);  s2a1 = fmaf(e0, d, s2a1);
            s2a2 = fmaf(e1, dt, s2a2);  s2a3 = fmaf(e1, d, s2a3);
            s1a0 += dt;  s1a1 += d;
            if (tid < 16) out[pathT + t] = __expf(lvn);   // wave 0, lanes 0-15
            lv = lvn;
        }
        // Race-freedom: hA(t+1) written post-B3(t), last hA read pre-B2(t);
        // hB(t+1) post-B1(t+1), last read pre-B3(t); hC(t+1) post-B2(t+1),
        // last read (L3) pre-B1(t+1) in every wave's program order.
    }
}

extern "C" void kernel_launch(void* const* d_in, const int* in_sizes, int n_in,
                              void* d_out, int out_size, void* d_ws, size_t ws_size,
                              hipStream_t stream) {
    const float* init_var = (const float*)d_in[0];
    const float* dtp      = (const float*)d_in[1];
    const float* dwg      = (const float*)d_in[2];
    const float* dW0 = (const float*)d_in[3];
    const float* dB0 = (const float*)d_in[4];
    const float* dW1 = (const float*)d_in[5];
    const float* dB1 = (const float*)d_in[6];
    const float* dW2 = (const float*)d_in[7];
    const float* dB2 = (const float*)d_in[8];
    const float* dW3 = (const float*)d_in[9];
    const float* dB3 = (const float*)d_in[10];
    const float* fW0 = (const float*)d_in[11];
    const float* fB0 = (const float*)d_in[12];
    const float* fW1 = (const float*)d_in[13];
    const float* fB1 = (const float*)d_in[14];
    const float* fW2 = (const float*)d_in[15];
    const float* fB2 = (const float*)d_in[16];
    const float* fW3 = (const float*)d_in[17];
    const float* fB3 = (const float*)d_in[18];
    float* out = (float*)d_out;

    sim_kernel<<<dim3(8192 / PPB), dim3(NT), 0, stream>>>(
        init_var, dtp, dwg,
        dW0, dB0, dW1, dB1, dW2, dB2, dW3, dB3,
        fW0, fB0, fW1, fB1, fW2, fB2, fW3, fB3,
        out);
}